// Round 2
// baseline (46.938 us; speedup 1.0000x reference)
//
#include <hip/hip_runtime.h>

// ATSS-style 1D regression loss (RegressionLoss_65936337928514).
//
// Sparse pipeline (no dense memset, no dense scan):
//   K1: per (image,gt) wave -> 135 candidate anchors (5 windows of 9 locs x3),
//       IoU mean+std threshold, writes compact candidate list and CLEARS only
//       the candidate slots of the dense (iou,~m) argmax buffer.
//   K2: compact list -> atomicMax of positive packs into dense buffer.
//   K3: one block per image walks the 8640 list entries, winners
//       (packed[b,a] == own pack) get smooth-L1; deterministic LDS reduce.

static constexpr int NLEV = 5;
static constexpr int B_IMG = 4;
static constexpr int M_GT = 64;
static constexpr int A_TOTAL = 190464;
static constexpr int K_CAND = 135;                 // 27 * 5
static constexpr int BM_TOTAL = B_IMG * M_GT;      // 256
static constexpr int SLOT_TOTAL = BM_TOTAL * K_CAND;   // 34560
static constexpr int SLOTS_PER_IMG = M_GT * K_CAND;    // 8640

__device__ __constant__ int d_LOCS[NLEV]   = {32768, 16384, 8192, 4096, 2048};
__device__ __constant__ int d_ASTART[NLEV] = {0, 98304, 147456, 172032, 184320};

// ---------------------------------------------------------------------------
// K1: one wave per (image, gt).
// Pack: high 32 = float bits of iou (positives have iou > 0, so uint order ==
// float order), low 32 = ~m (equal iou -> smaller m wins, matching argmax).
// Sentinel 0 = "no positive".
// ---------------------------------------------------------------------------
__global__ __launch_bounds__(64) void atss_candidates(
    const float* __restrict__ anchors,           // [A,2]
    const float* __restrict__ ann,               // [B,M,3]
    unsigned long long* __restrict__ packed,     // [B*A] (cleared sparsely here)
    int* __restrict__ cand,                      // [SLOT_TOTAL]: a if pos else -1
    unsigned long long* __restrict__ cpack)      // [SLOT_TOTAL]: pack if pos
{
    const int bm = blockIdx.x;
    const int b = bm >> 6;   // M_GT == 64
    const int m = bm & 63;
    const int lane = threadIdx.x;

    const float g0 = ann[(b * M_GT + m) * 3 + 0];
    const float g1 = ann[(b * M_GT + m) * 3 + 1];
    const float gcx = (g0 + g1) * 0.5f;

    // --- per-level window of 9 locations (wave-uniform) ---
    int winStart[NLEV];
#pragma unroll
    for (int lvl = 0; lvl < NLEV; ++lvl) {
        const int locs = d_LOCS[lvl];
        const int base = d_ASTART[lvl];
        const float stride = (float)(8 << lvl);

        auto cxof = [&](int t) -> float {
            const int a = base + 3 * t;
            return (anchors[2 * a] + anchors[2 * a + 1]) * 0.5f;
        };

        int j = (int)(gcx / stride);
        if (j < 0) j = 0;
        if (j > locs - 1) j = locs - 1;

        int bi = j;
        float bd = INFINITY;
        for (int t = j - 1; t <= j + 1; ++t) {
            if (t < 0 || t >= locs) continue;
            const float d = fabsf(cxof(t) - gcx);
            if (d < bd) { bd = d; bi = t; }
        }

        // two-pointer expansion to 9 locations; tie -> left (lower index),
        // matching jax.lax.top_k stable lower-index-first tie-breaking.
        int lo = bi, hi = bi;
#pragma unroll
        for (int s = 0; s < 8; ++s) {
            const float dl = (lo - 1 >= 0)   ? fabsf(cxof(lo - 1) - gcx) : INFINITY;
            const float dr = (hi + 1 < locs) ? fabsf(cxof(hi + 1) - gcx) : INFINITY;
            if (dl <= dr) --lo; else ++hi;
        }
        winStart[lvl] = lo;
    }

    // --- candidates: lane handles k = lane, lane+64, lane+128 ---
    float ci[3];
    int   ca[3];
    bool  cok[3];
#pragma unroll
    for (int i = 0; i < 3; ++i) {
        const int k = lane + 64 * i;
        ci[i] = 0.0f; ca[i] = -1; cok[i] = false;
        if (k < K_CAND) {
            const int lvl = k / 27;
            const int r = k % 27;
            const int loc = winStart[lvl] + r / 3;
            const int a = d_ASTART[lvl] + loc * 3 + (r % 3);
            const float a0 = anchors[2 * a];
            const float a1 = anchors[2 * a + 1];
            float inter = fminf(a1, g1) - fmaxf(a0, g0);
            inter = fmaxf(inter, 0.0f);
            const float uni = (a1 - a0) + (g1 - g0) - inter;
            const float iou = inter / fmaxf(uni, 1e-8f);
            const float cx = (a0 + a1) * 0.5f;
            ci[i] = iou;
            ca[i] = a;
            cok[i] = fminf(cx - g0, g1 - cx) > 0.01f;
        }
    }

    // --- mean / unbiased std over the 135 candidates (wave butterfly) ---
    float s = ci[0] + ci[1] + ci[2];
#pragma unroll
    for (int off = 32; off >= 1; off >>= 1) s += __shfl_xor(s, off);
    const float mean = s / 135.0f;

    float s2 = 0.0f;
#pragma unroll
    for (int i = 0; i < 3; ++i) {
        if (ca[i] >= 0) { const float d = ci[i] - mean; s2 += d * d; }
    }
#pragma unroll
    for (int off = 32; off >= 1; off >>= 1) s2 += __shfl_xor(s2, off);
    const float thresh = mean + sqrtf(s2 / 134.0f);

    // --- emit list entries + clear only our candidate slots of `packed` ---
    unsigned long long* pb = packed + (size_t)b * A_TOTAL;
#pragma unroll
    for (int i = 0; i < 3; ++i) {
        const int k = lane + 64 * i;
        if (ca[i] >= 0) {
            const int slot = bm * K_CAND + k;
            pb[ca[i]] = 0ULL;  // racing same-value stores across waves: benign
            const bool pos = cok[i] && (ci[i] >= thresh);
            cand[slot] = pos ? ca[i] : -1;
            if (pos) {
                const unsigned int bits = __float_as_uint(ci[i]);
                cpack[slot] =
                    ((unsigned long long)bits << 32) | (unsigned int)(~m);
            }
        }
    }
}

// ---------------------------------------------------------------------------
// K2: scatter positives into the (sparsely cleared) dense argmax buffer.
// ---------------------------------------------------------------------------
__global__ __launch_bounds__(256) void atss_scatter(
    const int* __restrict__ cand,
    const unsigned long long* __restrict__ cpack,
    unsigned long long* __restrict__ packed)
{
    const int slot = blockIdx.x * 256 + threadIdx.x;
    if (slot >= SLOT_TOTAL) return;
    const int a = cand[slot];
    if (a < 0) return;
    const int b = slot / SLOTS_PER_IMG;
    atomicMax(packed + (size_t)b * A_TOTAL + a, cpack[slot]);
}

// ---------------------------------------------------------------------------
// K3: one block per image. Winners = list entries whose pack equals the
// dense buffer's value at their anchor (unique: low bits hold ~m).
// Deterministic strided accumulation + LDS tree reduce.
// ---------------------------------------------------------------------------
__global__ __launch_bounds__(256) void atss_loss_reduce(
    const float* __restrict__ reg,               // [B,A,2]
    const float* __restrict__ anchors,           // [A,2]
    const float* __restrict__ ann,               // [B,M,3]
    const int* __restrict__ cand,
    const unsigned long long* __restrict__ cpack,
    const unsigned long long* __restrict__ packed,
    float* __restrict__ out)                     // [B]
{
    const int b = blockIdx.x;
    float loss = 0.0f;
    unsigned int cnt = 0;

    for (int s = threadIdx.x; s < SLOTS_PER_IMG; s += 256) {
        const int slot = b * SLOTS_PER_IMG + s;
        const int a = cand[slot];
        if (a < 0) continue;
        const unsigned long long pk = cpack[slot];
        if (packed[(size_t)b * A_TOTAL + a] != pk) continue;  // not the argmax

        const int m = (int)(~(unsigned int)(pk & 0xFFFFFFFFULL));
        const float g0 = ann[(b * M_GT + m) * 3 + 0];
        const float g1 = ann[(b * M_GT + m) * 3 + 1];
        const float a0 = anchors[2 * a];
        const float a1 = anchors[2 * a + 1];
        const float aw = a1 - a0;
        const float ac = a0 + 0.5f * aw;
        const float gwr = g1 - g0;
        const float gc = g0 + 0.5f * gwr;
        const float gw = fmaxf(gwr, 1.0f);
        const float dx = (gc - ac) / aw / 0.1f;
        const float dw = logf(gw / aw) / 0.2f;
        const float* r = reg + ((size_t)b * A_TOTAL + a) * 2;
        const float d0 = fabsf(dx - r[0]);
        const float d1 = fabsf(dw - r[1]);
        const float beta = 1.0f / 3.0f;
        const float l0 = (d0 <= beta) ? 0.5f * 3.0f * d0 * d0 : d0 - 0.5f / 3.0f;
        const float l1 = (d1 <= beta) ? 0.5f * 3.0f * d1 * d1 : d1 - 0.5f / 3.0f;
        loss += l0 + l1;
        cnt += 1;
    }

    __shared__ float sl[256];
    __shared__ unsigned int sc[256];
    sl[threadIdx.x] = loss;
    sc[threadIdx.x] = cnt;
    __syncthreads();
    for (int off = 128; off >= 1; off >>= 1) {
        if (threadIdx.x < off) {
            sl[threadIdx.x] += sl[threadIdx.x + off];
            sc[threadIdx.x] += sc[threadIdx.x + off];
        }
        __syncthreads();
    }
    if (threadIdx.x == 0) {
        const unsigned int np = sc[0];
        const unsigned int denom = (2u * np > 1u) ? 2u * np : 1u;
        out[b] = (np > 0) ? sl[0] / (float)denom : 0.0f;
    }
}

extern "C" void kernel_launch(void* const* d_in, const int* in_sizes, int n_in,
                              void* d_out, int out_size, void* d_ws, size_t ws_size,
                              hipStream_t stream) {
    const float* reg     = (const float*)d_in[0];  // [B,A,2]
    const float* anchors = (const float*)d_in[1];  // [A,2]
    const float* ann     = (const float*)d_in[2];  // [B,M,3]
    // d_in[3] = class_id (unused: reference keeps all rows)
    float* out = (float*)d_out;                    // [B]

    // ws layout (ws is 256 MiB; we use ~6.5 MB)
    unsigned long long* packed = (unsigned long long*)d_ws;             // [B*A]
    unsigned long long* cpack =
        (unsigned long long*)((char*)d_ws + (size_t)B_IMG * A_TOTAL * 8); // [SLOT_TOTAL]
    int* cand = (int*)((char*)cpack + (size_t)SLOT_TOTAL * 8);           // [SLOT_TOTAL]

    atss_candidates<<<BM_TOTAL, 64, 0, stream>>>(anchors, ann, packed, cand, cpack);
    atss_scatter<<<(SLOT_TOTAL + 255) / 256, 256, 0, stream>>>(cand, cpack, packed);
    atss_loss_reduce<<<B_IMG, 256, 0, stream>>>(reg, anchors, ann, cand, cpack,
                                                packed, out);
}